// Round 6
// baseline (11911.992 us; speedup 1.0000x reference)
//
#include <hip/hip_runtime.h>
#include <hip/hip_fp16.h>
#include <math.h>

typedef _Float16 f16;
typedef _Float16 f16x2 __attribute__((ext_vector_type(2)));
typedef _Float16 f16x4 __attribute__((ext_vector_type(4)));
typedef _Float16 f16x8 __attribute__((ext_vector_type(8)));
typedef float f32x2 __attribute__((ext_vector_type(2)));
typedef float f32x4 __attribute__((ext_vector_type(4)));
typedef unsigned int u32;
typedef unsigned long long u64;

#define NLAYER 3
#define BB 64           // combined batch (32 code + 32 comment)
#define TT 512          // seq len
#define HH 256          // hidden per direction
#define GG 768          // 3*H
#define EE 512          // per-layer input dim (=2H)
#define ROWS (BB*TT)    // 32768

// ---------------- helpers ----------------
__device__ __forceinline__ void load_lds16(const void* g, void* l) {
  __builtin_amdgcn_global_load_lds((const __attribute__((address_space(1))) u32*)g,
                                   (__attribute__((address_space(3))) u32*)l, 16, 0, 0);
}

// self-tagged 64-bit exchange word: hi32 = tag, lo32 = f32 payload.
// RELAXED agent-scope atomics: tag+data travel together, no fence needed.
__device__ __forceinline__ void publish(u64* p, u32 tag, float v) {
  u64 e = ((u64)tag << 32) | (u64)__builtin_bit_cast(u32, v);
  __hip_atomic_store(p, e, __ATOMIC_RELAXED, __HIP_MEMORY_SCOPE_AGENT);
}
__device__ __forceinline__ float wait_peer(const u64* p, u32 tag) {
  u64 e;
  for (;;) {
    e = __hip_atomic_load(p, __ATOMIC_RELAXED, __HIP_MEMORY_SCOPE_AGENT);
    if ((u32)(e >> 32) == tag) break;
    __builtin_amdgcn_s_sleep(1);
  }
  return __builtin_bit_cast(float, (u32)e);
}

__device__ __forceinline__ float sigm_fast(float x) { return 1.f / (1.f + __expf(-x)); }
__device__ __forceinline__ float tanh_fast(float x) { return 1.f - 2.f / (__expf(2.f * x) + 1.f); }

// ---------------- K0: Wx -> f16 hi/lo split, pre-transposed ----------------
__global__ __launch_bounds__(256) void prep_wx(
    const float* __restrict__ Wx, f16* __restrict__ Bth, f16* __restrict__ Btl)
{
  const int n_bt = NLAYER * 2 * GG * EE;     // 2,359,296
  const int stride = gridDim.x * blockDim.x;
  for (int e = blockIdx.x * blockDim.x + threadIdx.x; e < n_bt; e += stride) {
    int l = e / (2 * GG * EE); int r = e % (2 * GG * EE);
    int n = r / EE; int k = r % EE;
    int dr = n / GG; int j = n % GG;
    float w = Wx[(((size_t)(l * 2 + dr) * EE + k) * GG) + j];
    f16 hi = (f16)w;
    Bth[e] = hi;
    Btl[e] = (f16)(w - (float)hi);
  }
}

// ---------------- K1: embedding gather -> Xh/Xl f16 [32768][512] ----------------
__global__ __launch_bounds__(128) void gather_embed(
    const int* __restrict__ code_idx, const int* __restrict__ comment_idx,
    const float* __restrict__ table, f16* __restrict__ Xh, f16* __restrict__ Xl)
{
  const int r = blockIdx.x;  // rows 0..16383 = code, rest = comment
  const int idx = (r < 16384) ? code_idx[r] : comment_idx[r - 16384];
  const float4 v = ((const float4*)(table + (size_t)idx * EE))[threadIdx.x];
  f16x4 hi, lo;
  hi.x = (f16)v.x; lo.x = (f16)(v.x - (float)hi.x);
  hi.y = (f16)v.y; lo.y = (f16)(v.y - (float)hi.y);
  hi.z = (f16)v.z; lo.z = (f16)(v.z - (float)hi.z);
  hi.w = (f16)v.w; lo.w = (f16)(v.w - (float)hi.w);
  *(f16x4*)(Xh + (size_t)r * EE + threadIdx.x * 4) = hi;
  *(f16x4*)(Xl + (size_t)r * EE + threadIdx.x * 4) = lo;
}

// ---------------- K2: xp = (Ah+Al) @ (Bh+Bl)^T -> f32 [32768][1536] ----------------
__global__ __launch_bounds__(256) void gemm_split(
    const f16* __restrict__ Ah, const f16* __restrict__ Al,
    const f16* __restrict__ Bh, const f16* __restrict__ Bl,
    float* __restrict__ C)
{
  __shared__ __align__(16) f16 sAh[128 * 64];
  __shared__ __align__(16) f16 sAl[128 * 64];
  __shared__ __align__(16) f16 sBh[128 * 64];
  __shared__ __align__(16) f16 sBl[128 * 64];
  const int wg = blockIdx.x;
  const int nt = wg % 12;
  const int mt = wg / 12;
  const int t = threadIdx.x;
  const int lane = t & 63, wid = t >> 6;
  const int wr = wid >> 1, wc = wid & 1;

  f32x4 acc[4][4] = {};

  for (int ks_ = 0; ks_ < EE / 64; ++ks_) {
    const int k0 = ks_ * 64;
    if (ks_) __syncthreads();
    #pragma unroll
    for (int c = 0; c < 4; ++c) {
      const int s = c * 256 + t;
      const int row = s >> 3;
      const int g = (s & 7) ^ (row & 7);
      const size_t offA = (size_t)(mt * 128 + row) * EE + k0 + g * 8;
      const size_t offB = (size_t)(nt * 128 + row) * EE + k0 + g * 8;
      load_lds16(Ah + offA, sAh + s * 8);
      load_lds16(Al + offA, sAl + s * 8);
      load_lds16(Bh + offB, sBh + s * 8);
      load_lds16(Bl + offB, sBl + s * 8);
    }
    asm volatile("s_waitcnt vmcnt(0)" ::: "memory");
    __syncthreads();

    #pragma unroll
    for (int kk = 0; kk < 2; ++kk) {
      f16x8 ah[4], al[4], bh[4], bl[4];
      #pragma unroll
      for (int m = 0; m < 4; ++m) {
        const int r = wr * 64 + m * 16 + (lane & 15);
        const int gr = (kk * 4 + (lane >> 4)) ^ (r & 7);
        ah[m] = *(const f16x8*)((const char*)sAh + r * 128 + gr * 16);
        al[m] = *(const f16x8*)((const char*)sAl + r * 128 + gr * 16);
        const int cb = wc * 64 + m * 16 + (lane & 15);
        const int gb = (kk * 4 + (lane >> 4)) ^ (cb & 7);
        bh[m] = *(const f16x8*)((const char*)sBh + cb * 128 + gb * 16);
        bl[m] = *(const f16x8*)((const char*)sBl + cb * 128 + gb * 16);
      }
      #pragma unroll
      for (int m = 0; m < 4; ++m)
        #pragma unroll
        for (int n = 0; n < 4; ++n) {
          acc[m][n] = __builtin_amdgcn_mfma_f32_16x16x32_f16(ah[m], bh[n], acc[m][n], 0, 0, 0);
          acc[m][n] = __builtin_amdgcn_mfma_f32_16x16x32_f16(al[m], bh[n], acc[m][n], 0, 0, 0);
          acc[m][n] = __builtin_amdgcn_mfma_f32_16x16x32_f16(ah[m], bl[n], acc[m][n], 0, 0, 0);
        }
    }
  }

  const int crow0 = mt * 128 + wr * 64 + (lane >> 4) * 4;
  const int ccol0 = nt * 128 + wc * 64 + (lane & 15);
  #pragma unroll
  for (int m = 0; m < 4; ++m)
    #pragma unroll
    for (int n = 0; n < 4; ++n)
      #pragma unroll
      for (int q = 0; q < 4; ++q)
        C[(size_t)(crow0 + m * 16 + q) * (2 * GG) + ccol0 + n * 16] = acc[m][n][q];
}

// ---------------- K3: GRU recurrence, f32-exact, COLUMN-split over 2 CUs ----------------
// 256 WGs x 768 threads. WG w: job = w&127 -> (dir,b); kh = w>>7 owns h[kh*128..+128).
// This WG computes cols {z,r,hc}[gc] for gc in its h-half: gates are fully LOCAL.
// Thread t = q*384 + c (q: k-sub, c = g*128+jj): owns Wh[kq-slices][gc] = 128 f32 regs.
// Per step: A: local-k dot (all) || pollers fetch peer h(st-1);  B: sync;
//           C: remote-k dot;  D: sync;  E: gates local, h_new -> hsm + publish;  F: sync.
// Exchange = 128 tagged u64 per WG per step (depth-2 parity buffer, self-tagged).
__global__ __launch_bounds__(768, 3) void gru_cols(
    const float* __restrict__ xp,     // [32768][1536]
    const float* __restrict__ Wh,     // layer base: [2][256][768] f32
    const float* __restrict__ bias,   // [2][2][768]
    f16* __restrict__ Xh, f16* __restrict__ Xl,   // [32768][512] (l<2)
    float* __restrict__ states,      // [64][512]  (l==2)
    u64* __restrict__ xchg,           // [128 jobs][2 kh][2 parity][128]
    int last, int layer)
{
  const int w = blockIdx.x;          // 0..255
  const int job = w & 127;
  const int kh  = w >> 7;            // my h-half
  const int dir = job >> 6, b = job & 63;
  const int t = threadIdx.x;
  const int q = t >= 384;            // k sub-slice
  const int c = q ? t - 384 : t;     // 0..383
  const int g = c >> 7, jj = c & 127;
  const int gc = g * 256 + kh * 128 + jj;   // my global output column

  __shared__ __align__(16) float hsm[2 * 128];   // full h: [half][128]
  __shared__ float part[2][384];

  // resident recurrent weights (f32, exact): 64 local-k + 64 remote-k = 128 regs
  const int kloc = kh * 128 + q * 64;
  const int krem = (1 - kh) * 128 + q * 64;
  f32x2 wl[32], wr_[32];
  {
    const float* wb = Wh + (size_t)dir * (HH * GG) + gc;
    #pragma unroll
    for (int m = 0; m < 32; ++m) {
      wl[m]  = f32x2{wb[(size_t)(kloc + 2 * m) * GG], wb[(size_t)(kloc + 2 * m + 1) * GG]};
      wr_[m] = f32x2{wb[(size_t)(krem + 2 * m) * GG], wb[(size_t)(krem + 2 * m + 1) * GG]};
    }
  }

  // gate threads (t<128): biases for my 3 columns
  float b0z = 0.f, b0r = 0.f, b0h = 0.f, b1z = 0.f, b1r = 0.f, b1h = 0.f;
  if (t < 128) {
    const int cz = kh * 128 + t, cr = 256 + cz, ch = 512 + cz;
    b0z = bias[dir * 2 * GG + cz]; b1z = bias[dir * 2 * GG + GG + cz];
    b0r = bias[dir * 2 * GG + cr]; b1r = bias[dir * 2 * GG + GG + cr];
    b0h = bias[dir * 2 * GG + ch]; b1h = bias[dir * 2 * GG + GG + ch];
  }
  const float* xpb = xp + (size_t)b * TT * (2 * GG) + dir * GG + kh * 128;

  u64* pub = xchg + (size_t)(job * 2 + kh) * 256;
  const u64* peer = xchg + (size_t)(job * 2 + (1 - kh)) * 256;

  float hreg = 0.f;
  if (t < 256) hsm[t] = 0.f;
  __syncthreads();

  for (int st = 0; st < TT; ++st) {
    const int tt = dir ? (TT - 1 - st) : st;

    // ---- A: x issue + local-k dot (everyone); pollers fetch peer h(st-1) ----
    float xz = 0.f, xr = 0.f, xh = 0.f;
    if (t < 128) {                      // issue early; consumed at E
      const float* xrow = xpb + (size_t)tt * (2 * GG) + t;
      xz = xrow[0]; xr = xrow[256]; xh = xrow[512];
    }
    f32x2 a = {0.f, 0.f};
    {
      const float4* hp = (const float4*)(hsm + kloc);
      #pragma unroll
      for (int m = 0; m < 16; ++m) {
        const float4 h4 = hp[m];
        a = f32x2{h4.x, h4.y} * wl[2 * m] + a;
        a = f32x2{h4.z, h4.w} * wl[2 * m + 1] + a;
      }
    }
    if (st > 0 && t >= 640) {           // pollers: 128 threads, overlap w/ local dot
      const int pj = t - 640;
      const float pv = wait_peer(peer + ((st + 1) & 1) * 128 + pj,
                                 ((u32)layer << 16) | (u32)st);
      hsm[(1 - kh) * 128 + pj] = pv;
    }
    __syncthreads();   // B: peer half visible

    // ---- C: remote-k dot ----
    {
      const float4* hp = (const float4*)(hsm + krem);
      #pragma unroll
      for (int m = 0; m < 16; ++m) {
        const float4 h4 = hp[m];
        a = f32x2{h4.x, h4.y} * wr_[2 * m] + a;
        a = f32x2{h4.z, h4.w} * wr_[2 * m + 1] + a;
      }
    }
    part[q][c] = a.x + a.y;
    __syncthreads();   // D: partials visible

    // ---- E: gates (fully local), h update, publish ----
    if (t < 128) {
      const float rz = part[0][t]       + part[1][t]       + b1z;
      const float rr = part[0][128 + t] + part[1][128 + t] + b1r;
      const float rh = part[0][256 + t] + part[1][256 + t] + b1h;
      const float z = sigm_fast(xz + b0z + rz);
      const float r = sigm_fast(xr + b0r + rr);
      const float hh = tanh_fast(xh + b0h + r * rh);
      hreg = z * hreg + (1.f - z) * hh;
      hsm[kh * 128 + t] = hreg;
      if (st + 1 < TT)
        publish(pub + (st & 1) * 128 + t, ((u32)layer << 16) | (u32)(st + 1), hreg);
      if (!last) {
        const f16 hi = (f16)hreg;
        const size_t o = (size_t)(b * TT + tt) * EE + dir * HH + kh * 128 + t;
        Xh[o] = hi;
        Xl[o] = (f16)(hreg - (float)hi);
      } else if (st == TT - 1) {
        states[(size_t)b * (2 * HH) + dir * HH + kh * 128 + t] = hreg;
      }
    }
    __syncthreads();   // F: hsm local half updated for next A
  }
}

// ---------------- K4: leaks + BN1 + FC1 + BN2 + cls + sigmoid ----------------
__global__ __launch_bounds__(256) void final_head(
    const float* __restrict__ states, const float* __restrict__ leaks_in,
    const float* __restrict__ leaks_W, const float* __restrict__ leaks_b,
    const float* __restrict__ bn1g, const float* __restrict__ bn1b,
    const float* __restrict__ bn1m, const float* __restrict__ bn1v,
    const float* __restrict__ fc1W, const float* __restrict__ fc1b,
    const float* __restrict__ bn2g, const float* __restrict__ bn2b,
    const float* __restrict__ bn2m, const float* __restrict__ bn2v,
    const float* __restrict__ clsW, const float* __restrict__ clsb,
    float* __restrict__ out)
{
  const int b = blockIdx.x;   // 0..31
  const int c = threadIdx.x;  // 0..255
  __shared__ float vec[1280];
  __shared__ float red[256];

  float acc = leaks_b[c];
  for (int k = 0; k < 148; ++k) acc += leaks_in[b * 148 + k] * leaks_W[k * 256 + c];
  vec[1024 + c] = fmaxf(acc, 0.f);
  for (int i = c; i < 512; i += 256) {
    vec[i] = states[(size_t)b * 512 + i];
    vec[512 + i] = states[(size_t)(b + 32) * 512 + i];
  }
  __syncthreads();
  for (int i = c; i < 1280; i += 256)
    vec[i] = (vec[i] - bn1m[i]) * rsqrtf(bn1v[i] + 1e-3f) * bn1g[i] + bn1b[i];
  __syncthreads();
  float a1 = fc1b[c];
  for (int i = 0; i < 1280; ++i) a1 += vec[i] * fc1W[i * 256 + c];
  a1 = fmaxf(a1, 0.f);
  a1 = (a1 - bn2m[c]) * rsqrtf(bn2v[c] + 1e-3f) * bn2g[c] + bn2b[c];
  red[c] = a1 * clsW[c];
  __syncthreads();
  for (int s = 128; s > 0; s >>= 1) { if (c < s) red[c] += red[c + s]; __syncthreads(); }
  if (c == 0) out[b] = 1.f / (1.f + expf(-(red[0] + clsb[0])));
}

// ---------------- launch ----------------
extern "C" void kernel_launch(void* const* d_in, const int* in_sizes, int n_in,
                              void* d_out, int out_size, void* d_ws, size_t ws_size,
                              hipStream_t stream) {
  const int*   comment_idx = (const int*)d_in[0];
  const int*   code_idx    = (const int*)d_in[2];
  const float* leaks_in    = (const float*)d_in[4];
  const float* table       = (const float*)d_in[6];
  const float* Wx          = (const float*)d_in[7];
  const float* Wh          = (const float*)d_in[8];
  const float* gb          = (const float*)d_in[9];
  const float* leaks_W     = (const float*)d_in[10];
  const float* leaks_b     = (const float*)d_in[11];
  const float* bn1g = (const float*)d_in[12];
  const float* bn1b = (const float*)d_in[13];
  const float* bn1m = (const float*)d_in[14];
  const float* bn1v = (const float*)d_in[15];
  const float* fc1W = (const float*)d_in[16];
  const float* fc1b = (const float*)d_in[17];
  const float* bn2g = (const float*)d_in[18];
  const float* bn2b = (const float*)d_in[19];
  const float* bn2m = (const float*)d_in[20];
  const float* bn2v = (const float*)d_in[21];
  const float* clsW = (const float*)d_in[22];
  const float* clsb = (const float*)d_in[23];
  float* out = (float*)d_out;

  // workspace layout (~278.5 MB)
  char* ws = (char*)d_ws;
  f16*   Xh     = (f16*)(ws);                       //  33,554,432 B
  f16*   Xl     = (f16*)(ws + 33554432);            //  33,554,432 B
  float* xp     = (float*)(ws + 67108864);          // 201,326,592 B
  f16*   Bth    = (f16*)(ws + 268435456);           //   4,718,592 B
  f16*   Btl    = (f16*)(ws + 273154048);           //   4,718,592 B
  float* states = (float*)(ws + 277872640);         //     131,072 B
  u64*   xchg   = (u64*)(ws + 278003712);           //     524,288 B (self-tagged, no init)

  prep_wx<<<dim3(1024), dim3(256), 0, stream>>>(Wx, Bth, Btl);
  gather_embed<<<dim3(ROWS), dim3(128), 0, stream>>>(code_idx, comment_idx, table, Xh, Xl);

  const int gemm_grid = (ROWS / 128) * (2 * GG / 128);  // 3072
  const size_t btl_stride = (size_t)2 * GG * EE;
  const size_t wh_stride  = (size_t)2 * HH * GG;

  for (int l = 0; l < NLAYER; ++l) {
    gemm_split<<<dim3(gemm_grid), dim3(256), 0, stream>>>(
        Xh, Xl, Bth + l * btl_stride, Btl + l * btl_stride, xp);
    gru_cols<<<dim3(256), dim3(768), 0, stream>>>(
        xp, Wh + l * wh_stride, gb + l * 2 * 2 * GG,
        Xh, Xl, states, xchg, l == NLAYER - 1, l);
  }

  final_head<<<dim3(32), dim3(256), 0, stream>>>(states, leaks_in, leaks_W, leaks_b,
                                                 bn1g, bn1b, bn1m, bn1v, fc1W, fc1b,
                                                 bn2g, bn2b, bn2m, bn2v, clsW, clsb, out);
}